// Round 15
// baseline (47.650 us; speedup 1.0000x reference)
//
#include <hip/hip_runtime.h>
#include <math.h>

// Problem constants
#define BB   16
#define HH   112
#define WW   112
#define CC   64
#define KK   8
#define EPSF 1e-6f
#define LN2F 0.69314718055994530942f

#define WPT  7   // outputs in w per thread (wave covers 7 w, block 28)
#define HPT  2   // output rows per block (packed as float2 lanes)
#define NR   10  // rows loaded: h0-4 .. h0+5
// block: 256 threads = 64 ch x 4 w-groups; grid = B*(H/2)*(W/28) = 3584
// XCD swizzle: 3584 = 8 x 448; each XCD gets a contiguous tile range.
// NOTE: __launch_bounds__(256,3) is load-bearing — tightening it (r4: (256,4),
// r12: (256,6)) makes the allocator shrink VGPRs and break the deep load
// clauses (r12: VGPR 84->40, spill traffic 500 MB, 2.7x slowdown).
// NEW (r15): chunk order rotated per wave (even: 0,5,10; odd: 10,5,0) to
// DESYNCHRONIZE the waves' load-burst phases on each CU — all waves formerly
// hit identical s_waitcnt walls in lockstep (correlated stalls; VALUBusy 53%).

typedef float v2f __attribute__((ext_vector_type(2)));

// Load NC columns x 10 rows; vertical sums for row-pair packed as v2f;
// packed horizontal masked accumulation into mu[4][WPT].
template<bool HE, bool WE, int I0, int NC>
__device__ __forceinline__ void process_chunk(const float* __restrict__ x,
                                              const int* rowoff,     // block-uniform
                                              const float* rvalid,
                                              int w0, int c, int voff0,
                                              v2f* mu1, v2f* mu2, v2f* mu3, v2f* mu4,
                                              float* arawA, float* arawB)
{
    float a[NC][NR];
    if constexpr (!WE) {
#pragma unroll
        for (int j = 0; j < NC; ++j) {
            const int co = voff0 + (I0 + j) * CC;
#pragma unroll
            for (int dh = 0; dh < NR; ++dh)
                a[j][dh] = x[rowoff[dh] + co];
        }
    } else {
        int coloff[NC];
#pragma unroll
        for (int j = 0; j < NC; ++j) {
            const int wc  = w0 - 4 + I0 + j;
            const int wcc = min(max(wc, 0), WW - 1);   // clamp -> valid addr
            coloff[j] = wcc * CC + c;
        }
#pragma unroll
        for (int j = 0; j < NC; ++j)
#pragma unroll
            for (int dh = 0; dh < NR; ++dh)
                a[j][dh] = x[rowoff[dh] + coloff[j]];
    }

    // raw center-row values for owned outputs (local col i = wi+4)
#pragma unroll
    for (int j = 0; j < NC; ++j) {
        const int i = I0 + j;
        if (i >= 4 && i <= 10) { arawA[i - 4] = a[j][4]; arawB[i - 4] = a[j][5]; }
    }

#pragma unroll
    for (int j = 0; j < NC; ++j) {
        const int i = I0 + j;
        float v0 = fabsf(a[j][0]);
        float v1 = fabsf(a[j][1]);
        float v2 = fabsf(a[j][2]);
        float v3 = fabsf(a[j][3]);
        float v4 = fabsf(a[j][4]);
        float v5 = fabsf(a[j][5]);
        float v6 = fabsf(a[j][6]);
        float v7 = fabsf(a[j][7]);
        float v8 = fabsf(a[j][8]);
        float v9 = fabsf(a[j][9]);
        if (HE) {
            v0 *= rvalid[0]; v1 *= rvalid[1]; v2 *= rvalid[2]; v3 *= rvalid[3];
            v4 *= rvalid[4]; v5 *= rvalid[5]; v6 *= rvalid[6]; v7 *= rvalid[7];
            v8 *= rvalid[8]; v9 *= rvalid[9];
        }
        // row h0 vertical windows, row h0+1 incrementally
        const float tA1 = v3 + v4 + v5;
        const float tA2 = tA1 + v2 + v6;
        const float tA3 = tA2 + v1 + v7;
        const float tA4 = tA3 + v0 + v8;
        v2f t1 = { tA1, tA1 + (v6 - v3) };
        v2f t2 = { tA2, tA2 + (v7 - v2) };
        v2f t3 = { tA3, tA3 + (v8 - v1) };
        v2f t4 = { tA4, tA4 + (v9 - v0) };
        if (WE) {
            const bool ok = (unsigned)(w0 - 4 + i) < (unsigned)WW;
            const float m = ok ? 1.0f : 0.0f;
            t1 *= m; t2 *= m; t3 *= m; t4 *= m;
        }
#pragma unroll
        for (int wi = 0; wi < WPT; ++wi) {
            const int ci = wi + 4;
            if (i >= ci - 1 && i <= ci + 1) mu1[wi] += t1;
            if (i >= ci - 2 && i <= ci + 2) mu2[wi] += t2;
            if (i >= ci - 3 && i <= ci + 3) mu3[wi] += t3;
            if (i >= ci - 4 && i <= ci + 4) mu4[wi] += t4;
        }
    }
}

template<bool HE, bool WE, int ORDER>
__device__ __forceinline__ void do_tile(const float* __restrict__ x,
                                        float* __restrict__ out,
                                        int b, int h0, int w0, int c,
                                        float s1, float s2, float s3, float s4,
                                        const float* cen, const float* wid)
{
    int rowoff[NR];         // block-uniform element offsets of the 10 rows
    float rvalid[NR];
#pragma unroll
    for (int dh = 0; dh < NR; ++dh) {
        const int hr = h0 + dh - 4;
        const int hc = HE ? min(max(hr, 0), HH - 1) : hr;
        rowoff[dh] = (b * HH + hc) * WW * CC;
        rvalid[dh] = HE ? (((unsigned)hr < (unsigned)HH) ? 1.0f : 0.0f) : 1.0f;
    }

    const int voff0 = (w0 - 4) * CC + c;   // valid (>=0) whenever !WE

    v2f mu1[WPT], mu2[WPT], mu3[WPT], mu4[WPT];
    float arawA[WPT], arawB[WPT];
#pragma unroll
    for (int i = 0; i < WPT; ++i) {
        mu1[i] = (v2f)0.0f; mu2[i] = (v2f)0.0f;
        mu3[i] = (v2f)0.0f; mu4[i] = (v2f)0.0f;
    }

    // Wave-phase stagger: even waves walk chunks left->right, odd waves
    // right->left. Float sums reassociated per wave but order is FIXED per
    // thread -> deterministic output across calls.
    if constexpr (ORDER == 0) {
        process_chunk<HE, WE, 0,  5>(x, rowoff, rvalid, w0, c, voff0, mu1, mu2, mu3, mu4, arawA, arawB);
        process_chunk<HE, WE, 5,  5>(x, rowoff, rvalid, w0, c, voff0, mu1, mu2, mu3, mu4, arawA, arawB);
        process_chunk<HE, WE, 10, 5>(x, rowoff, rvalid, w0, c, voff0, mu1, mu2, mu3, mu4, arawA, arawB);
    } else {
        process_chunk<HE, WE, 10, 5>(x, rowoff, rvalid, w0, c, voff0, mu1, mu2, mu3, mu4, arawA, arawB);
        process_chunk<HE, WE, 5,  5>(x, rowoff, rvalid, w0, c, voff0, mu1, mu2, mu3, mu4, arawA, arawB);
        process_chunk<HE, WE, 0,  5>(x, rowoff, rvalid, w0, c, voff0, mu1, mu2, mu3, mu4, arawA, arawB);
    }

    // eps row counts for the two rows (packed)
    v2f r1 = {3.f, 3.f}, r2 = {5.f, 5.f}, r3 = {7.f, 7.f}, r4 = {9.f, 9.f};
    if (HE) {
        const int gA = h0, gB = h0 + 1;
        r1 = (v2f){ (float)(min(gA+1,HH-1)-max(gA-1,0)+1), (float)(min(gB+1,HH-1)-max(gB-1,0)+1) };
        r2 = (v2f){ (float)(min(gA+2,HH-1)-max(gA-2,0)+1), (float)(min(gB+2,HH-1)-max(gB-2,0)+1) };
        r3 = (v2f){ (float)(min(gA+3,HH-1)-max(gA-3,0)+1), (float)(min(gB+3,HH-1)-max(gB-3,0)+1) };
        r4 = (v2f){ (float)(min(gA+4,HH-1)-max(gA-4,0)+1), (float)(min(gB+4,HH-1)-max(gB-4,0)+1) };
    }

    float* __restrict__ orowA = out + rowoff[4];
    float* __restrict__ orowB = out + rowoff[5];
    const int voffC = w0 * CC + c;
    const v2f zero = (v2f)0.0f;

#pragma unroll
    for (int wi = 0; wi < WPT; ++wi) {
        float c1 = 3.f, c2 = 5.f, c3 = 7.f, c4 = 9.f;
        if (WE) {
            const int w = w0 + wi;
            c1 = (float)(min(w + 1, WW - 1) - max(w - 1, 0) + 1);
            c2 = (float)(min(w + 2, WW - 1) - max(w - 2, 0) + 1);
            c3 = (float)(min(w + 3, WW - 1) - max(w - 3, 0) + 1);
            c4 = (float)(min(w + 4, WW - 1) - max(w - 4, 0) + 1);
        }
        const v2f m1 = mu1[wi] + r1 * (c1 * EPSF);
        const v2f m2 = mu2[wi] + r2 * (c2 * EPSF);
        const v2f m3 = mu3[wi] + r3 * (c3 * EPSF);
        const v2f m4 = mu4[wi] + r4 * (c4 * EPSF);

        const v2f l1 = { __log2f(m1.x), __log2f(m1.y) };
        const v2f l2 = { __log2f(m2.x), __log2f(m2.y) };
        const v2f l3 = { __log2f(m3.x), __log2f(m3.y) };
        const v2f l4 = { __log2f(m4.x), __log2f(m4.y) };

        const v2f alpha = l1 * s1 + l2 * s2 + l3 * s3 + l4 * s4;

        v2f sc = zero;
#pragma unroll
        for (int k = 0; k < KK; ++k) {
            const v2f d  = alpha - cen[k];
            const v2f hv = 1.0f - wid[k] * (d * d);
            sc += __builtin_elementwise_max(hv, zero);
        }

        const float sigA = __fdividef(1.0f, 1.0f + __expf(-sc.x));
        const float sigB = __fdividef(1.0f, 1.0f + __expf(-sc.y));
        // nontemporal: out is write-once, never re-read -> keep L2 for input
        __builtin_nontemporal_store(arawA[wi] + sigA, orowA + voffC + wi * CC);
        __builtin_nontemporal_store(arawB[wi] + sigB, orowB + voffC + wi * CC);
    }
}

__global__ __launch_bounds__(256, 3)
void l2hist_singularity_kernel(const float* __restrict__ x,
                               const float* __restrict__ sw,
                               const float* __restrict__ centers,
                               const float* __restrict__ widths,
                               float* __restrict__ out)
{
    const int tid = threadIdx.x;
    const int c   = tid & 63;        // lanes contiguous in channel -> coalesced
    const int wq  = tid >> 6;        // wave index (w0 is wave-uniform)

    // Bijective chunked XCD swizzle: 3584 blocks = 8 XCDs x 448.
    const int blk = (blockIdx.x & 7) * 448 + (blockIdx.x >> 3);

    const int wt  = blk & 3;
    const int ht  = (blk >> 2) % (HH / HPT);
    const int b   = (blk >> 2) / (HH / HPT);
    const int h0  = ht * HPT;
    const int w0  = wt * 28 + wq * WPT;

    const float s1 = sw[0] * LN2F, s2 = sw[1] * LN2F;
    const float s3 = sw[2] * LN2F, s4 = sw[3] * LN2F;

    float cen[KK], wid[KK];
#pragma unroll
    for (int k = 0; k < KK; ++k) {
        cen[k] = centers[c * KK + k];
        wid[k] = widths[c * KK + k];
    }

    const bool he = (h0 < 4) | (h0 + HPT - 1 + 4 >= HH);   // block-uniform
    const bool we = (w0 < 4) | (w0 + WPT - 1 + 4 >= WW);   // wave-uniform
    const bool rev = (wq & 1);                             // wave-uniform

    if (!he) {
        if (!we) { if (!rev) do_tile<false, false, 0>(x, out, b, h0, w0, c, s1, s2, s3, s4, cen, wid);
                   else      do_tile<false, false, 1>(x, out, b, h0, w0, c, s1, s2, s3, s4, cen, wid); }
        else     { if (!rev) do_tile<false, true,  0>(x, out, b, h0, w0, c, s1, s2, s3, s4, cen, wid);
                   else      do_tile<false, true,  1>(x, out, b, h0, w0, c, s1, s2, s3, s4, cen, wid); }
    } else {
        if (!we) { if (!rev) do_tile<true,  false, 0>(x, out, b, h0, w0, c, s1, s2, s3, s4, cen, wid);
                   else      do_tile<true,  false, 1>(x, out, b, h0, w0, c, s1, s2, s3, s4, cen, wid); }
        else     { if (!rev) do_tile<true,  true,  0>(x, out, b, h0, w0, c, s1, s2, s3, s4, cen, wid);
                   else      do_tile<true,  true,  1>(x, out, b, h0, w0, c, s1, s2, s3, s4, cen, wid); }
    }
}

extern "C" void kernel_launch(void* const* d_in, const int* in_sizes, int n_in,
                              void* d_out, int out_size, void* d_ws, size_t ws_size,
                              hipStream_t stream) {
    const float* x       = (const float*)d_in[0];
    const float* sw      = (const float*)d_in[1];
    const float* centers = (const float*)d_in[2];
    const float* widths  = (const float*)d_in[3];
    float* out           = (float*)d_out;

    const int blocks = BB * (HH / HPT) * (WW / 28);   // 3584
    l2hist_singularity_kernel<<<blocks, 256, 0, stream>>>(x, sw, centers, widths, out);
}

// Round 16
// 46.226 us; speedup vs baseline: 1.0308x; 1.0308x over previous
//
#include <hip/hip_runtime.h>
#include <math.h>

// Problem constants
#define BB   16
#define HH   112
#define WW   112
#define CC   64
#define KK   8
#define EPSF 1e-6f
#define LN2F 0.69314718055994530942f

#define WPT  7   // outputs in w per thread (wave covers 7 w, block 28)
#define HPT  2   // output rows per block (packed as float2 lanes)
#define NR   10  // rows loaded: h0-4 .. h0+5
// block: 256 threads = 64 ch x 4 w-groups; grid = B*(H/2)*(W/28) = 3584
// XCD swizzle: 3584 = 8 x 448; each XCD gets a contiguous tile range.
// NOTE: __launch_bounds__ 2nd arg must stay PERMISSIVE — tightening it
// (r4: (256,4), r12: (256,6)) makes the allocator shrink VGPRs and break the
// deep load clauses (r12: VGPR 84->40, 500 MB spill traffic, 2.7x slowdown).
// r16: chunk loop now ONLY produces vertical sums t_r[15] (no accumulation
// interleaved with loads); horizontal windows via 4 short independent sliding
// chains in the epilogue (68 packed ops vs 360). t storage ~100 VGPR is free
// because residency has been pinned at 8 waves/CU for 10 rounds regardless.

typedef float v2f __attribute__((ext_vector_type(2)));

// Load NC columns x 10 rows; per column build the 4 vertical window sums
// (row-pair packed as v2f) and store into t arrays. No mu accumulation here.
template<bool HE, bool WE, int I0, int NC>
__device__ __forceinline__ void process_chunk(const float* __restrict__ x,
                                              const int* rowoff,     // block-uniform
                                              const float* rvalid,
                                              int w0, int c, int voff0,
                                              v2f* t1, v2f* t2, v2f* t3, v2f* t4,
                                              float* arawA, float* arawB)
{
    float a[NC][NR];
    if constexpr (!WE) {
#pragma unroll
        for (int j = 0; j < NC; ++j) {
            const int co = voff0 + (I0 + j) * CC;
#pragma unroll
            for (int dh = 0; dh < NR; ++dh)
                a[j][dh] = x[rowoff[dh] + co];
        }
    } else {
        int coloff[NC];
#pragma unroll
        for (int j = 0; j < NC; ++j) {
            const int wc  = w0 - 4 + I0 + j;
            const int wcc = min(max(wc, 0), WW - 1);   // clamp -> valid addr
            coloff[j] = wcc * CC + c;
        }
#pragma unroll
        for (int j = 0; j < NC; ++j)
#pragma unroll
            for (int dh = 0; dh < NR; ++dh)
                a[j][dh] = x[rowoff[dh] + coloff[j]];
    }

    // raw center-row values for owned outputs (local col i = wi+4)
#pragma unroll
    for (int j = 0; j < NC; ++j) {
        const int i = I0 + j;
        if (i >= 4 && i <= 10) { arawA[i - 4] = a[j][4]; arawB[i - 4] = a[j][5]; }
    }

#pragma unroll
    for (int j = 0; j < NC; ++j) {
        const int i = I0 + j;
        float v0 = fabsf(a[j][0]);
        float v1 = fabsf(a[j][1]);
        float v2 = fabsf(a[j][2]);
        float v3 = fabsf(a[j][3]);
        float v4 = fabsf(a[j][4]);
        float v5 = fabsf(a[j][5]);
        float v6 = fabsf(a[j][6]);
        float v7 = fabsf(a[j][7]);
        float v8 = fabsf(a[j][8]);
        float v9 = fabsf(a[j][9]);
        if (HE) {
            v0 *= rvalid[0]; v1 *= rvalid[1]; v2 *= rvalid[2]; v3 *= rvalid[3];
            v4 *= rvalid[4]; v5 *= rvalid[5]; v6 *= rvalid[6]; v7 *= rvalid[7];
            v8 *= rvalid[8]; v9 *= rvalid[9];
        }
        // row h0 vertical windows, row h0+1 incrementally
        const float tA1 = v3 + v4 + v5;
        const float tA2 = tA1 + v2 + v6;
        const float tA3 = tA2 + v1 + v7;
        const float tA4 = tA3 + v0 + v8;
        v2f T1 = { tA1, tA1 + (v6 - v3) };
        v2f T2 = { tA2, tA2 + (v7 - v2) };
        v2f T3 = { tA3, tA3 + (v8 - v1) };
        v2f T4 = { tA4, tA4 + (v9 - v0) };
        if (WE) {
            const bool ok = (unsigned)(w0 - 4 + i) < (unsigned)WW;
            const float m = ok ? 1.0f : 0.0f;
            T1 *= m; T2 *= m; T3 *= m; T4 *= m;
        }
        t1[i] = T1; t2[i] = T2; t3[i] = T3; t4[i] = T4;
    }
}

template<bool HE, bool WE>
__device__ __forceinline__ void do_tile(const float* __restrict__ x,
                                        float* __restrict__ out,
                                        int b, int h0, int w0, int c,
                                        float s1, float s2, float s3, float s4,
                                        const float* cen, const float* wid)
{
    int rowoff[NR];         // block-uniform element offsets of the 10 rows
    float rvalid[NR];
#pragma unroll
    for (int dh = 0; dh < NR; ++dh) {
        const int hr = h0 + dh - 4;
        const int hc = HE ? min(max(hr, 0), HH - 1) : hr;
        rowoff[dh] = (b * HH + hc) * WW * CC;
        rvalid[dh] = HE ? (((unsigned)hr < (unsigned)HH) ? 1.0f : 0.0f) : 1.0f;
    }

    const int voff0 = (w0 - 4) * CC + c;   // valid (>=0) whenever !WE

    v2f t1[15], t2[15], t3[15], t4[15];
    float arawA[WPT], arawB[WPT];

    process_chunk<HE, WE, 0,  5>(x, rowoff, rvalid, w0, c, voff0, t1, t2, t3, t4, arawA, arawB);
    process_chunk<HE, WE, 5,  5>(x, rowoff, rvalid, w0, c, voff0, t1, t2, t3, t4, arawA, arawB);
    process_chunk<HE, WE, 10, 5>(x, rowoff, rvalid, w0, c, voff0, t1, t2, t3, t4, arawA, arawB);

    // running horizontal windows for output 0 (center local col 4)
    v2f w3 = t1[3] + t1[4] + t1[5];
    v2f w5 = t2[2] + t2[3] + t2[4] + t2[5] + t2[6];
    v2f w7 = t3[1] + t3[2] + t3[3] + t3[4] + t3[5] + t3[6] + t3[7];
    v2f w9 = t4[0] + t4[1] + t4[2] + t4[3] + t4[4] + t4[5] + t4[6] + t4[7] + t4[8];

    // eps row counts for the two rows (packed)
    v2f r1 = {3.f, 3.f}, r2 = {5.f, 5.f}, r3 = {7.f, 7.f}, r4 = {9.f, 9.f};
    if (HE) {
        const int gA = h0, gB = h0 + 1;
        r1 = (v2f){ (float)(min(gA+1,HH-1)-max(gA-1,0)+1), (float)(min(gB+1,HH-1)-max(gB-1,0)+1) };
        r2 = (v2f){ (float)(min(gA+2,HH-1)-max(gA-2,0)+1), (float)(min(gB+2,HH-1)-max(gB-2,0)+1) };
        r3 = (v2f){ (float)(min(gA+3,HH-1)-max(gA-3,0)+1), (float)(min(gB+3,HH-1)-max(gB-3,0)+1) };
        r4 = (v2f){ (float)(min(gA+4,HH-1)-max(gA-4,0)+1), (float)(min(gB+4,HH-1)-max(gB-4,0)+1) };
    }

    float* __restrict__ orowA = out + rowoff[4];
    float* __restrict__ orowB = out + rowoff[5];
    const int voffC = w0 * CC + c;
    const v2f zero = (v2f)0.0f;

#pragma unroll
    for (int wi = 0; wi < WPT; ++wi) {
        float c1 = 3.f, c2 = 5.f, c3 = 7.f, c4 = 9.f;
        if (WE) {
            const int w = w0 + wi;
            c1 = (float)(min(w + 1, WW - 1) - max(w - 1, 0) + 1);
            c2 = (float)(min(w + 2, WW - 1) - max(w - 2, 0) + 1);
            c3 = (float)(min(w + 3, WW - 1) - max(w - 3, 0) + 1);
            c4 = (float)(min(w + 4, WW - 1) - max(w - 4, 0) + 1);
        }
        const v2f m1 = w3 + r1 * (c1 * EPSF);
        const v2f m2 = w5 + r2 * (c2 * EPSF);
        const v2f m3 = w7 + r3 * (c3 * EPSF);
        const v2f m4 = w9 + r4 * (c4 * EPSF);

        const v2f l1 = { __log2f(m1.x), __log2f(m1.y) };
        const v2f l2 = { __log2f(m2.x), __log2f(m2.y) };
        const v2f l3 = { __log2f(m3.x), __log2f(m3.y) };
        const v2f l4 = { __log2f(m4.x), __log2f(m4.y) };

        const v2f alpha = l1 * s1 + l2 * s2 + l3 * s3 + l4 * s4;

        v2f sc = zero;
#pragma unroll
        for (int k = 0; k < KK; ++k) {
            const v2f d  = alpha - cen[k];
            const v2f hv = 1.0f - wid[k] * (d * d);
            sc += __builtin_elementwise_max(hv, zero);
        }

        const float sigA = __fdividef(1.0f, 1.0f + __expf(-sc.x));
        const float sigB = __fdividef(1.0f, 1.0f + __expf(-sc.y));
        // nontemporal: out is write-once, never re-read -> keep L2 for input
        __builtin_nontemporal_store(arawA[wi] + sigA, orowA + voffC + wi * CC);
        __builtin_nontemporal_store(arawB[wi] + sigB, orowB + voffC + wi * CC);

        // slide the 4 windows one column right (short independent chains;
        // sums are nonnegative -> cancellation harmless at this tolerance)
        if (wi < WPT - 1) {
            w3 += t1[wi + 6] - t1[wi + 3];
            w5 += t2[wi + 7] - t2[wi + 2];
            w7 += t3[wi + 8] - t3[wi + 1];
            w9 += t4[wi + 9] - t4[wi + 0];
        }
    }
}

__global__ __launch_bounds__(256, 2)
void l2hist_singularity_kernel(const float* __restrict__ x,
                               const float* __restrict__ sw,
                               const float* __restrict__ centers,
                               const float* __restrict__ widths,
                               float* __restrict__ out)
{
    const int tid = threadIdx.x;
    const int c   = tid & 63;        // lanes contiguous in channel -> coalesced
    const int wq  = tid >> 6;        // wave index (w0 is wave-uniform)

    // Bijective chunked XCD swizzle: 3584 blocks = 8 XCDs x 448.
    const int blk = (blockIdx.x & 7) * 448 + (blockIdx.x >> 3);

    const int wt  = blk & 3;
    const int ht  = (blk >> 2) % (HH / HPT);
    const int b   = (blk >> 2) / (HH / HPT);
    const int h0  = ht * HPT;
    const int w0  = wt * 28 + wq * WPT;

    const float s1 = sw[0] * LN2F, s2 = sw[1] * LN2F;
    const float s3 = sw[2] * LN2F, s4 = sw[3] * LN2F;

    float cen[KK], wid[KK];
#pragma unroll
    for (int k = 0; k < KK; ++k) {
        cen[k] = centers[c * KK + k];
        wid[k] = widths[c * KK + k];
    }

    const bool he = (h0 < 4) | (h0 + HPT - 1 + 4 >= HH);   // block-uniform
    const bool we = (w0 < 4) | (w0 + WPT - 1 + 4 >= WW);   // wave-uniform

    if (!he) {
        if (!we) do_tile<false, false>(x, out, b, h0, w0, c, s1, s2, s3, s4, cen, wid);
        else     do_tile<false, true >(x, out, b, h0, w0, c, s1, s2, s3, s4, cen, wid);
    } else {
        if (!we) do_tile<true,  false>(x, out, b, h0, w0, c, s1, s2, s3, s4, cen, wid);
        else     do_tile<true,  true >(x, out, b, h0, w0, c, s1, s2, s3, s4, cen, wid);
    }
}

extern "C" void kernel_launch(void* const* d_in, const int* in_sizes, int n_in,
                              void* d_out, int out_size, void* d_ws, size_t ws_size,
                              hipStream_t stream) {
    const float* x       = (const float*)d_in[0];
    const float* sw      = (const float*)d_in[1];
    const float* centers = (const float*)d_in[2];
    const float* widths  = (const float*)d_in[3];
    float* out           = (float*)d_out;

    const int blocks = BB * (HH / HPT) * (WW / 28);   // 3584
    l2hist_singularity_kernel<<<blocks, 256, 0, stream>>>(x, sw, centers, widths, out);
}